// Round 13
// baseline (137.080 us; speedup 1.0000x reference)
//
#include <hip/hip_runtime.h>
#include <hip/hip_bf16.h>
#include <cstdint>
#include <cstddef>

#define NN 1024
#define FF 256

typedef __attribute__((ext_vector_type(8))) short bf16x8;
typedef __attribute__((ext_vector_type(4))) float f32x4;

typedef __attribute__((address_space(1))) const void* gas_ptr;
typedef __attribute__((address_space(3))) void* las_ptr;

__device__ __forceinline__ short f2bf(float x) {
  unsigned int u = __float_as_uint(x);
  u = (u + 0x7fffu + ((u >> 16) & 1u)) >> 16;   // RNE
  return (short)u;
}

// ---- PT tiled layout (all bf16 matrices) ----
// 16-row x 32-k tiles (512 elems): elem(row,k) = ((k&31)>>3)*128 + (row&15)*8 + (k&7)
// A wave load at (tile_base + lane*8) IS the MFMA fragment:
//   lane -> (row = lane&15, k = (lane>>4)*8 + j)
// Ahat (1024x1024/bw): bw<<20 + (r>>4)<<14 + (k>>5)<<9 + pt(r,k)
// G    (F x 1024/bw) : bw*F*1024 + (f>>4)<<14 + (n>>5)<<9 + pt(f,n)
// WT   (F_OUT x 256) : (fo>>4)*4096 + (fi>>5)<<9 + pt(fo,fi)

// ---- fused: d = rsqrt(rowsum(adj)+1), Ahat = (adj+I) bf16 PT-tiled ---------
__global__ __launch_bounds__(256)
void dinv_cast(const float* __restrict__ adj, float* __restrict__ dinv,
               short* __restrict__ Ahat) {
  __shared__ float wsum[64];
  int b = blockIdx.x;                          // 0..2047 = bw*64 + stripe
  int bw = b >> 6, s = b & 63;
  int t = threadIdx.x;
  int wid = t >> 6, lane = t & 63;
  int row = lane & 15;                         // local row in stripe
  int rloc = (s << 4) + row;                   // row in matrix
  int kg = (lane >> 4) & 3;
  const float* arow = adj + ((size_t)(bw << 10) + rloc) * NN;
  short* outb = Ahat + ((size_t)bw << 20) + ((size_t)s << 14) + (t << 3);
  float ssum = 0.f;
  #pragma unroll
  for (int it = 0; it < 8; it++) {
    int col = (it << 7) + (wid << 5) + (kg << 3);
    float4 a0 = *(const float4*)(arow + col);
    float4 a1 = *(const float4*)(arow + col + 4);
    float v[8] = {a0.x, a0.y, a0.z, a0.w, a1.x, a1.y, a1.z, a1.w};
    union { ushort o[8]; int4 q; } pk;
    #pragma unroll
    for (int j = 0; j < 8; j++) {
      v[j] += (rloc == col + j) ? 1.f : 0.f;
      ssum += v[j];
      pk.o[j] = (ushort)f2bf(v[j]);
    }
    *(int4*)(outb + (it << 11)) = pk.q;
  }
  ssum += __shfl_down(ssum, 32, 64);
  ssum += __shfl_down(ssum, 16, 64);
  if (lane < 16) wsum[(wid << 4) + lane] = ssum;
  __syncthreads();
  if (t < 16) {
    float tot = wsum[t] + wsum[16 + t] + wsum[32 + t] + wsum[48 + t];
    dinv[(bw << 10) + (s << 4) + t] = rsqrtf(tot);
  }
}

// ---- merged: X -> G1 (d-scaled, PT) AND W1/W2/W3 -> WT (PT) ----------------
__global__ __launch_bounds__(256)
void preproc_xw(const float* __restrict__ X, const float* __restrict__ dinv,
                short* __restrict__ XT,
                const float* __restrict__ W1, const float* __restrict__ W2,
                const float* __restrict__ W3,
                short* __restrict__ T1, short* __restrict__ T2,
                short* __restrict__ T3) {
  __shared__ short T[64][72];
  int b = blockIdx.x;
  int t = threadIdx.x;
  if (b < 2048) {
    int bwo = b >> 6;
    int n0 = (b & 15) << 6, f0 = ((b >> 4) & 3) << 6;
    {
      int n = t >> 2, fc = (t & 3) << 4;
      float dn = dinv[(bwo << 10) + n0 + n];
      const float* src = X + (((size_t)bwo * NN + n0 + n) * FF) + f0 + fc;
      #pragma unroll
      for (int i = 0; i < 4; i++) {
        float4 v = ((const float4*)src)[i];
        ushort4 p;
        p.x = (unsigned short)f2bf(v.x * dn); p.y = (unsigned short)f2bf(v.y * dn);
        p.z = (unsigned short)f2bf(v.z * dn); p.w = (unsigned short)f2bf(v.w * dn);
        *(ushort4*)&T[n][fc + (i << 2)] = p;
      }
    }
    __syncthreads();
    {
      int f = t >> 2, nc = (t & 3) << 4;
      int fg = f0 + f, ng = n0 + nc;
      short tmp[16];
      #pragma unroll
      for (int i = 0; i < 16; i++) tmp[i] = T[nc + i][f];
      size_t e0 = ((size_t)bwo << 18) + ((size_t)(fg >> 4) << 14) + ((ng >> 5) << 9)
                + (((ng & 31) >> 3) << 7) + ((fg & 15) << 3);
      *(int4*)(XT + e0)       = *(int4*)&tmp[0];
      *(int4*)(XT + e0 + 128) = *(int4*)&tmp[8];
    }
  } else {
    int idx = (b - 2048) * 256 + t;            // 0..163839
    const float* W; short* Td; int FO; int loc;
    if (idx < 65536)       { W = W1; Td = T1; FO = 256; loc = idx; }
    else if (idx < 131072) { W = W2; Td = T2; FO = 256; loc = idx - 65536; }
    else                   { W = W3; Td = T3; FO = 128; loc = idx - 131072; }
    int fo = loc >> 8, fi = loc & 255;
    if (fo < FO) {
      size_t e = (size_t)((fo >> 4) << 12) + ((fi >> 5) << 9)
               + (((fi & 31) >> 3) << 7) + ((fo & 15) << 3) + (fi & 7);
      Td[e] = f2bf(W[fi * FO + fo]);
    }
  }
}

// ---------------- fused layer ----------------------------------------------
// Grid 256 (8 XCD x 4 bw x 8 rb), 256 thr (4 waves = 4 wf), 1 block/CU,
// 1 wave/SIMD (512-VGPR budget). Block tile: 128 r x 256 f; wave 128 r x 64 f
// (acc 4x8). wr=1 -> H has ZERO L2 duplication (32 KB unique/block/step); A
// LDS-staged dbuf (16 KB/step, x4 reuse via LDS pipe). Per-XCD L2 demand
// drops 2.5 -> 1.5 MB/step. Stage-first + vmcnt(8) skeleton from R12.
template<int F_OUT, bool FINAL>
__global__ __launch_bounds__(256, 1)
void gcn_layer(const short* __restrict__ Ahat,    // PT tiled (A+I) bf16
               const float* __restrict__ dinv,
               const short* __restrict__ Gin,     // PT tiled g = d*h, F=256
               const short* __restrict__ WT,      // PT tiled
               const float* __restrict__ bias,
               short* __restrict__ Gout,          // PT tiled, F_OUT
               float* __restrict__ Out) {         // [32][1024][F_OUT] fp32
  __shared__ __align__(16) short lds[34816];      // A dbuf 2x16KB; aggL[128][272] overlays

  int b = blockIdx.x;
  int x = b & 7, m = b >> 3;
  int bw = (x << 2) + (m >> 3);                   // same-XCD neighbors share bw
  int rb = m & 7;
  int r0 = rb << 7;                               // 128 rows / block

  int tid = threadIdx.x;
  int wf = tid >> 6, lane = tid & 63;             // 4 waves = 4 f-slices
  int l15 = lane & 15, l4 = lane >> 4;            // l4 in 0..3

  const float* dvB = dinv + (bw << 10);
  const short* Hb = Gin + ((size_t)bw << 18) + ((size_t)(wf << 2) << 14) + (lane << 3);
  const short* Abase = Ahat + ((size_t)bw << 20) + ((size_t)(rb << 3) << 14);

  // stage A-tile rows r0..r0+127 for K64 tile t -> buf sel (16KB linear)
  auto stageA = [&](int sel, int t) {
    char* base = (char*)lds + (sel << 14);
    #pragma unroll
    for (int i = 0; i < 4; i++) {
      int slot = (i << 8) + tid;                  // 0..1023, 16B each
      int c = slot >> 6, o = slot & 63;           // chunk (stripe,ktile), 16B unit
      const short* g = Abase + ((size_t)(c >> 1) << 14)
                     + ((size_t)((t << 1) + (c & 1)) << 9) + (o << 3);
      __builtin_amdgcn_global_load_lds((gas_ptr)g, (las_ptr)(base + (slot << 4)), 16, 0, 0);
    }
  };

  f32x4 acc[4][8];                                // [ah(f)][aa(r)]
  #pragma unroll
  for (int ah = 0; ah < 4; ah++)
    #pragma unroll
    for (int aa = 0; aa < 8; aa++) acc[ah][aa] = f32x4{0.f, 0.f, 0.f, 0.f};

  bf16x8 hE[4][2], hO[4][2];

#define LOADH(HB, T)                                                          \
  { _Pragma("unroll")                                                         \
    for (int ah = 0; ah < 4; ah++) {                                          \
      HB[ah][0] = *(const bf16x8*)(Hb + ah * 16384 + (size_t)(2 * (T)) * 512);\
      HB[ah][1] = *(const bf16x8*)(Hb + ah * 16384 + (size_t)(2 * (T) + 1) * 512); } }

// read 4 A-stripes (aa0..aa0+3) and do their 32 MFMA; halves transient VGPR
#define MMHALF(HB, PAR, AA0)                                                  \
  { const char* ab_ = (const char*)lds + ((PAR) << 14);                       \
    bf16x8 aT[4][2];                                                          \
    _Pragma("unroll")                                                         \
    for (int q = 0; q < 4; q++) {                                             \
      int c_ = (((AA0) + q) << 1);                                            \
      aT[q][0] = *(const bf16x8*)(ab_ + (c_ << 10) + (lane << 4));            \
      aT[q][1] = *(const bf16x8*)(ab_ + ((c_ + 1) << 10) + (lane << 4));      \
    }                                                                         \
    __builtin_amdgcn_s_setprio(1);                                            \
    _Pragma("unroll")                                                         \
    for (int kt = 0; kt < 2; kt++)                                            \
      _Pragma("unroll")                                                       \
      for (int ah = 0; ah < 4; ah++)                                          \
        _Pragma("unroll")                                                     \
        for (int q = 0; q < 4; q++)                                           \
          acc[ah][(AA0) + q] = __builtin_amdgcn_mfma_f32_16x16x32_bf16(       \
              HB[ah][kt], aT[q][kt], acc[ah][(AA0) + q], 0, 0, 0);            \
    __builtin_amdgcn_s_setprio(0); }

  stageA(0, 0);
  __builtin_amdgcn_sched_barrier(0);
  LOADH(hE, 0);
  asm volatile("s_waitcnt vmcnt(8)" ::: "memory");   // stage(0) done; hE flying
  __builtin_amdgcn_sched_barrier(0);
  __builtin_amdgcn_s_barrier();

  #pragma unroll
  for (int it = 0; it < 8; ++it) {
    const int t0 = 2 * it, t1 = t0 + 1;
    // ---- even body: compute tile t0 from buf0 with hE ----
    if (t0 < 15) stageA(1, t1);                    // issue stage FIRST
    __builtin_amdgcn_sched_barrier(0);             // pin order: stage < H-loads
    if (t0 < 15) LOADH(hO, t1);
    MMHALF(hE, 0, 0);
    MMHALF(hE, 0, 4);
    if (t0 < 15) { asm volatile("s_waitcnt vmcnt(8)" ::: "memory"); }
    else         { asm volatile("s_waitcnt vmcnt(0)" ::: "memory"); }
    __builtin_amdgcn_sched_barrier(0);
    __builtin_amdgcn_s_barrier();
    if (t1 > 15) break;
    // ---- odd body: compute tile t1 from buf1 with hO ----
    if (t1 < 15) stageA(0, t1 + 1);
    __builtin_amdgcn_sched_barrier(0);
    if (t1 < 15) LOADH(hE, t1 + 1);
    MMHALF(hO, 1, 0);
    MMHALF(hO, 1, 4);
    if (t1 < 15) { asm volatile("s_waitcnt vmcnt(8)" ::: "memory"); }
    else         { asm volatile("s_waitcnt vmcnt(0)" ::: "memory"); }
    __builtin_amdgcn_sched_barrier(0);
    __builtin_amdgcn_s_barrier();
  }
#undef LOADH
#undef MMHALF

  // ---- agg = d[r]*acc -> LDS bf16 [128][272], XOR-swizzled (overlays bufs) ----
  short* aggL = lds;
  float dsc[8];
  #pragma unroll
  for (int aa = 0; aa < 8; aa++) dsc[aa] = dvB[r0 + (aa << 4) + l15];
  #pragma unroll
  for (int ah = 0; ah < 4; ah++)
    #pragma unroll
    for (int aa = 0; aa < 8; aa++) {
      int r = (aa << 4) + l15;
      int fB = ((wf << 6) + (ah << 4) + (l4 << 2)) << 1;   // byte col
      int off = (r * 544 + (fB ^ ((r & 7) << 4))) >> 1;
      ushort4 p;
      p.x = (unsigned short)f2bf(acc[ah][aa][0] * dsc[aa]);
      p.y = (unsigned short)f2bf(acc[ah][aa][1] * dsc[aa]);
      p.z = (unsigned short)f2bf(acc[ah][aa][2] * dsc[aa]);
      p.w = (unsigned short)f2bf(acc[ah][aa][3] * dsc[aa]);
      *(ushort4*)(aggL + off) = p;
    }
  __syncthreads();

  // ---- stage 2: out = relu(agg @ W + b), K = 256, W from L2 ----
  constexpr int NFO = F_OUT / 64;                 // fo-tiles per wave
  const short* Wbase = WT + (size_t)(wf * NFO) * 4096 + (lane << 3);
  f32x4 acc2[8][NFO];
  #pragma unroll
  for (int am = 0; am < 8; am++)
    #pragma unroll
    for (int nf = 0; nf < NFO; nf++) acc2[am][nf] = f32x4{0.f, 0.f, 0.f, 0.f};

  #pragma unroll
  for (int kt = 0; kt < 8; kt++) {
    bf16x8 af[8];
    #pragma unroll
    for (int am = 0; am < 8; am++) {
      int r = (am << 4) + l15;
      int fB = (kt << 6) + (l4 << 4);
      af[am] = *(const bf16x8*)(aggL + ((r * 544 + (fB ^ ((r & 7) << 4))) >> 1));
    }
    #pragma unroll
    for (int nf = 0; nf < NFO; nf++) {
      bf16x8 wv = *(const bf16x8*)(Wbase + (size_t)nf * 4096 + (kt << 9));
      #pragma unroll
      for (int am = 0; am < 8; am++)
        acc2[am][nf] = __builtin_amdgcn_mfma_f32_16x16x32_bf16(af[am], wv, acc2[am][nf], 0, 0, 0);
    }
  }

  // ---- epilogue: bias + relu (+d[node] for g-form) + store ----
  #pragma unroll
  for (int am = 0; am < 8; am++) {
    int nodeLoc = (am << 4) + (l4 << 2);          // + j
    float4 dn4 = *(const float4*)(dvB + r0 + nodeLoc);
    float dn[4] = {dn4.x, dn4.y, dn4.z, dn4.w};
    #pragma unroll
    for (int nf = 0; nf < NFO; nf++) {
      int fo = wf * (F_OUT / 4) + (nf << 4) + l15;
      float bb = bias[fo];
      float v[4];
      #pragma unroll
      for (int j = 0; j < 4; j++) v[j] = fmaxf(acc2[am][nf][j] + bb, 0.f);
      if (!FINAL) {
        ushort4 p;
        p.x = (unsigned short)f2bf(v[0] * dn[0]);
        p.y = (unsigned short)f2bf(v[1] * dn[1]);
        p.z = (unsigned short)f2bf(v[2] * dn[2]);
        p.w = (unsigned short)f2bf(v[3] * dn[3]);
        size_t e = (size_t)bw * (F_OUT * 1024) + ((size_t)(fo >> 4) << 14)
                 + ((size_t)((rb << 2) + (am >> 1)) << 9)
                 + ((size_t)(((am & 1) << 1) + (l4 >> 1)) << 7)
                 + ((fo & 15) << 3) + ((l4 & 1) << 2);
        *(ushort4*)(Gout + e) = p;
      } else {
        float* ob = Out + ((size_t)(bw << 10) + r0 + nodeLoc) * F_OUT + fo;
        ob[0]         = v[0];
        ob[F_OUT]     = v[1];
        ob[2 * F_OUT] = v[2];
        ob[3 * F_OUT] = v[3];
      }
    }
  }
}

extern "C" void kernel_launch(void* const* d_in, const int* in_sizes, int n_in,
                              void* d_out, int out_size, void* d_ws, size_t ws_size,
                              hipStream_t stream) {
  const float* X   = (const float*)d_in[0];
  const float* adj = (const float*)d_in[1];
  const float* W1  = (const float*)d_in[2];
  const float* b1  = (const float*)d_in[3];
  const float* W2  = (const float*)d_in[4];
  const float* b2  = (const float*)d_in[5];
  const float* W3  = (const float*)d_in[6];
  const float* b3  = (const float*)d_in[7];
  float* out = (float*)d_out;

  char* ws = (char*)d_ws;
  float* dinv = (float*)ws;                              // 128 KB
  short* WT1  = (short*)(ws + 131072);                   // 128 KB
  short* WT2  = (short*)(ws + 262144);                   // 128 KB
  short* WT3  = (short*)(ws + 393216);                   //  64 KB
  short* bufA = (short*)(ws + 458752);                   //  16 MB
  short* bufB = (short*)(ws + 458752 + 16777216);        //  16 MB
  short* Ahat = (short*)(ws + 458752 + 2 * 16777216);    //  64 MB

  dinv_cast<<<2048, 256, 0, stream>>>(adj, dinv, Ahat);
  preproc_xw<<<2688, 256, 0, stream>>>(X, dinv, bufA, W1, W2, W3, WT1, WT2, WT3);

  gcn_layer<256, false><<<256, 256, 0, stream>>>(Ahat, dinv, bufA, WT1, b1, bufB, nullptr);
  gcn_layer<256, false><<<256, 256, 0, stream>>>(Ahat, dinv, bufB, WT2, b2, bufA, nullptr);
  gcn_layer<128, true ><<<256, 256, 0, stream>>>(Ahat, dinv, bufA, WT3, b3, nullptr, out);
}

// Round 15
// 130.733 us; speedup vs baseline: 1.0485x; 1.0485x over previous
//
#include <hip/hip_runtime.h>
#include <hip/hip_bf16.h>
#include <cstdint>
#include <cstddef>

#define NN 1024
#define FF 256

typedef __attribute__((ext_vector_type(8))) short bf16x8;
typedef __attribute__((ext_vector_type(4))) float f32x4;

typedef __attribute__((address_space(1))) const void* gas_ptr;
typedef __attribute__((address_space(3))) void* las_ptr;

__device__ __forceinline__ short f2bf(float x) {
  unsigned int u = __float_as_uint(x);
  u = (u + 0x7fffu + ((u >> 16) & 1u)) >> 16;   // RNE
  return (short)u;
}

// ---- PT tiled layout (all bf16 matrices) ----
// 16-row x 32-k tiles (512 elems): elem(row,k) = ((k&31)>>3)*128 + (row&15)*8 + (k&7)
// Wave load at (tile_base + lane*8) IS the MFMA fragment.
// Ahat (1024x1024/bw): bw<<20 + (r>>4)<<14 + (k>>5)<<9 + pt(r,k)
// G    (F x 1024/bw) : bw*F*1024 + (f>>4)<<14 + (n>>5)<<9 + pt(f,n)
// WT   (F_OUT x 256) : (fo>>4)*4096 + (fi>>5)<<9 + pt(fo,fi)

// ---- fused: d = rsqrt(rowsum(adj)+1), Ahat = (adj+I) bf16 PT-tiled ---------
__global__ __launch_bounds__(256)
void dinv_cast(const float* __restrict__ adj, float* __restrict__ dinv,
               short* __restrict__ Ahat) {
  __shared__ float wsum[64];
  int b = blockIdx.x;                          // 0..2047 = bw*64 + stripe
  int bw = b >> 6, s = b & 63;
  int t = threadIdx.x;
  int wid = t >> 6, lane = t & 63;
  int row = lane & 15;
  int rloc = (s << 4) + row;
  int kg = (lane >> 4) & 3;
  const float* arow = adj + ((size_t)(bw << 10) + rloc) * NN;
  short* outb = Ahat + ((size_t)bw << 20) + ((size_t)s << 14) + (t << 3);
  float ssum = 0.f;
  #pragma unroll
  for (int it = 0; it < 8; it++) {
    int col = (it << 7) + (wid << 5) + (kg << 3);
    float4 a0 = *(const float4*)(arow + col);
    float4 a1 = *(const float4*)(arow + col + 4);
    float v[8] = {a0.x, a0.y, a0.z, a0.w, a1.x, a1.y, a1.z, a1.w};
    union { ushort o[8]; int4 q; } pk;
    #pragma unroll
    for (int j = 0; j < 8; j++) {
      v[j] += (rloc == col + j) ? 1.f : 0.f;
      ssum += v[j];
      pk.o[j] = (ushort)f2bf(v[j]);
    }
    *(int4*)(outb + (it << 11)) = pk.q;
  }
  ssum += __shfl_down(ssum, 32, 64);
  ssum += __shfl_down(ssum, 16, 64);
  if (lane < 16) wsum[(wid << 4) + lane] = ssum;
  __syncthreads();
  if (t < 16) {
    float tot = wsum[t] + wsum[16 + t] + wsum[32 + t] + wsum[48 + t];
    dinv[(bw << 10) + (s << 4) + t] = rsqrtf(tot);
  }
}

// ---- merged: X -> G1 (d-scaled, PT) AND W1/W2/W3 -> WT (PT) ----------------
__global__ __launch_bounds__(256)
void preproc_xw(const float* __restrict__ X, const float* __restrict__ dinv,
                short* __restrict__ XT,
                const float* __restrict__ W1, const float* __restrict__ W2,
                const float* __restrict__ W3,
                short* __restrict__ T1, short* __restrict__ T2,
                short* __restrict__ T3) {
  __shared__ short T[64][72];
  int b = blockIdx.x;
  int t = threadIdx.x;
  if (b < 2048) {
    int bwo = b >> 6;
    int n0 = (b & 15) << 6, f0 = ((b >> 4) & 3) << 6;
    {
      int n = t >> 2, fc = (t & 3) << 4;
      float dn = dinv[(bwo << 10) + n0 + n];
      const float* src = X + (((size_t)bwo * NN + n0 + n) * FF) + f0 + fc;
      #pragma unroll
      for (int i = 0; i < 4; i++) {
        float4 v = ((const float4*)src)[i];
        ushort4 p;
        p.x = (unsigned short)f2bf(v.x * dn); p.y = (unsigned short)f2bf(v.y * dn);
        p.z = (unsigned short)f2bf(v.z * dn); p.w = (unsigned short)f2bf(v.w * dn);
        *(ushort4*)&T[n][fc + (i << 2)] = p;
      }
    }
    __syncthreads();
    {
      int f = t >> 2, nc = (t & 3) << 4;
      int fg = f0 + f, ng = n0 + nc;
      short tmp[16];
      #pragma unroll
      for (int i = 0; i < 16; i++) tmp[i] = T[nc + i][f];
      size_t e0 = ((size_t)bwo << 18) + ((size_t)(fg >> 4) << 14) + ((ng >> 5) << 9)
                + (((ng & 31) >> 3) << 7) + ((fg & 15) << 3);
      *(int4*)(XT + e0)       = *(int4*)&tmp[0];
      *(int4*)(XT + e0 + 128) = *(int4*)&tmp[8];
    }
  } else {
    int idx = (b - 2048) * 256 + t;
    const float* W; short* Td; int FO; int loc;
    if (idx < 65536)       { W = W1; Td = T1; FO = 256; loc = idx; }
    else if (idx < 131072) { W = W2; Td = T2; FO = 256; loc = idx - 65536; }
    else                   { W = W3; Td = T3; FO = 128; loc = idx - 131072; }
    int fo = loc >> 8, fi = loc & 255;
    if (fo < FO) {
      size_t e = (size_t)((fo >> 4) << 12) + ((fi >> 5) << 9)
               + (((fi & 31) >> 3) << 7) + ((fo & 15) << 3) + (fi & 7);
      Td[e] = f2bf(W[fi * FO + fo]);
    }
  }
}

// ---------------- fused layer: 8-phase-style fine interleave ----------------
// Grid 256, 512 thr (8 waves = 2wr x 4wf), 1 block/CU. Block 128r x 256f.
// 3-buffer LDS ring (3 x 48KB bytes: A 16KB + H 32KB per K64 tile). Per tile:
// 2 phases, each {3 gload_lds (tile t+2) || 8 ds_read_b128 -> barrier ->
// lgkmcnt(0) -> setprio+16 MFMA -> barrier}. Counted vmcnt(6) once per tile.
template<int F_OUT, bool FINAL>
__global__ __launch_bounds__(512)
void gcn_layer(const short* __restrict__ Ahat,    // PT tiled (A+I) bf16
               const float* __restrict__ dinv,
               const short* __restrict__ Gin,     // PT tiled g = d*h, F=256
               const short* __restrict__ WT,      // PT tiled
               const float* __restrict__ bias,
               short* __restrict__ Gout,          // PT tiled, F_OUT
               float* __restrict__ Out) {         // [32][1024][F_OUT] fp32
  __shared__ __align__(16) short lds[73728];      // 3 x 49152 B ring; aggL overlays

  int b = blockIdx.x;
  int x = b & 7, m = b >> 3;
  int bw = (x << 2) + (m >> 3);                   // same-XCD neighbors share bw
  int rb = m & 7;
  int r0 = rb << 7;                               // 128 rows / block

  int tid = threadIdx.x;
  int wid = tid >> 6, lane = tid & 63;
  int l15 = lane & 15, l4 = lane >> 4;
  int wr = wid >> 2, wf = wid & 3;

  const float* dvB = dinv + (bw << 10);
  const short* Abase = Ahat + ((size_t)bw << 20) + ((size_t)(rb << 3) << 14);
  const short* Hbase = Gin + ((size_t)bw << 18);

  // 6 loads/thread per K64 tile: j=0,1 -> A (16KB), j=2..5 -> H (32KB).
  // half 0 issues j=0..2, half 1 issues j=3..5.
  auto stage3 = [&](int sel, int t, int half) {
    char* base = (char*)lds + sel * 49152;        // 48 KB per ring buffer
    int kb = t << 1;
    #pragma unroll
    for (int i = 0; i < 3; i++) {
      int j = half * 3 + i;
      int slot = (j << 9) + tid;                  // 0..3071, 16B each
      const short* g;
      if (j < 2) {                                // A region: slot 0..1023
        int c = slot >> 6, o = slot & 63;
        g = Abase + ((size_t)(c >> 1) << 14) + ((size_t)(kb + (c & 1)) << 9) + (o << 3);
      } else {                                    // H region: slot-1024 in 0..2047
        int s2 = slot - 1024;
        int c = s2 >> 6, o = s2 & 63;
        g = Hbase + ((size_t)(c >> 1) << 14) + ((size_t)(kb + (c & 1)) << 9) + (o << 3);
      }
      __builtin_amdgcn_global_load_lds((gas_ptr)g, (las_ptr)(base + (slot << 4)), 16, 0, 0);
    }
  };

  f32x4 acc[4][4];                                // [ah(f)][aa(r)]
  #pragma unroll
  for (int ah = 0; ah < 4; ah++)
    #pragma unroll
    for (int aa = 0; aa < 4; aa++) acc[ah][aa] = f32x4{0.f, 0.f, 0.f, 0.f};

  // prologue: tiles 0,1 staged into bufs 0,1; wait tile0 (oldest 6)
  stage3(0, 0, 0); stage3(0, 0, 1);
  stage3(1, 1, 0); stage3(1, 1, 1);
  asm volatile("s_waitcnt vmcnt(6)" ::: "memory");
  __builtin_amdgcn_sched_barrier(0);
  __builtin_amdgcn_s_barrier();

  #pragma unroll
  for (int t = 0; t < 16; ++t) {
    const char* base = (const char*)lds + (t % 3) * 49152;
    #pragma unroll
    for (int p = 0; p < 2; ++p) {
      if (t <= 13) stage3((t + 2) % 3, t + 2, p);
      bf16x8 aT[4], hT[4];
      #pragma unroll
      for (int aa = 0; aa < 4; aa++) {
        int c = (((wr << 2) + aa) << 1) + p;
        aT[aa] = *(const bf16x8*)(base + (c << 10) + (lane << 4));
      }
      #pragma unroll
      for (int ah = 0; ah < 4; ah++) {
        int c = (((wf << 2) + ah) << 1) + p;
        hT[ah] = *(const bf16x8*)(base + 16384 + (c << 10) + (lane << 4));
      }
      __builtin_amdgcn_s_barrier();               // phase-lock waves
      asm volatile("s_waitcnt lgkmcnt(0)" ::: "memory");
      __builtin_amdgcn_sched_barrier(0);
      __builtin_amdgcn_s_setprio(1);
      #pragma unroll
      for (int ah = 0; ah < 4; ah++)
        #pragma unroll
        for (int aa = 0; aa < 4; aa++)
          acc[ah][aa] = __builtin_amdgcn_mfma_f32_16x16x32_bf16(
              hT[ah], aT[aa], acc[ah][aa], 0, 0, 0);
      __builtin_amdgcn_s_setprio(0);
      if (p == 1 && t <= 13) {                    // next tile's buf must be ready
        asm volatile("s_waitcnt vmcnt(6)" ::: "memory");
        __builtin_amdgcn_sched_barrier(0);
      } else if (p == 1 && t == 14) {
        asm volatile("s_waitcnt vmcnt(0)" ::: "memory");
        __builtin_amdgcn_sched_barrier(0);
      }
      __builtin_amdgcn_s_barrier();               // after this, next data readable
    }
  }

  // ---- agg = d[r]*acc -> LDS bf16 [128][272], XOR-swizzled (overlays ring) ----
  short* aggL = lds;
  float dsc[4];
  #pragma unroll
  for (int aa = 0; aa < 4; aa++) dsc[aa] = dvB[r0 + (wr << 6) + (aa << 4) + l15];
  #pragma unroll
  for (int ah = 0; ah < 4; ah++)
    #pragma unroll
    for (int aa = 0; aa < 4; aa++) {
      int r = (wr << 6) + (aa << 4) + l15;
      int fB = ((wf << 6) + (ah << 4) + (l4 << 2)) << 1;   // byte col
      int off = (r * 544 + (fB ^ ((r & 7) << 4))) >> 1;
      ushort4 p;
      p.x = (unsigned short)f2bf(acc[ah][aa][0] * dsc[aa]);
      p.y = (unsigned short)f2bf(acc[ah][aa][1] * dsc[aa]);
      p.z = (unsigned short)f2bf(acc[ah][aa][2] * dsc[aa]);
      p.w = (unsigned short)f2bf(acc[ah][aa][3] * dsc[aa]);
      *(ushort4*)(aggL + off) = p;
    }
  __syncthreads();

  // ---- stage 2: out = relu(agg @ W + b), K = 256, W from L2 ----
  constexpr int NFO = F_OUT / 64;                 // fo-tiles per wave
  const short* Wbase = WT + (size_t)(wf * NFO) * 4096 + (lane << 3);
  f32x4 acc2[4][NFO];
  #pragma unroll
  for (int am = 0; am < 4; am++)
    #pragma unroll
    for (int nf = 0; nf < NFO; nf++) acc2[am][nf] = f32x4{0.f, 0.f, 0.f, 0.f};

  #pragma unroll
  for (int kt = 0; kt < 8; kt++) {
    bf16x8 af[4];
    #pragma unroll
    for (int am = 0; am < 4; am++) {
      int r = (wr << 6) + (am << 4) + l15;
      int fB = (kt << 6) + (l4 << 4);
      af[am] = *(const bf16x8*)(aggL + ((r * 544 + (fB ^ ((r & 7) << 4))) >> 1));
    }
    #pragma unroll
    for (int nf = 0; nf < NFO; nf++) {
      bf16x8 wv = *(const bf16x8*)(Wbase + (size_t)nf * 4096 + (kt << 9));
      #pragma unroll
      for (int am = 0; am < 4; am++)
        acc2[am][nf] = __builtin_amdgcn_mfma_f32_16x16x32_bf16(af[am], wv, acc2[am][nf], 0, 0, 0);
    }
  }

  // ---- epilogue: bias + relu (+d[node] for g-form) + store ----
  #pragma unroll
  for (int am = 0; am < 4; am++) {
    int nodeLoc = (wr << 6) + (am << 4) + (l4 << 2);
    float4 dn4 = *(const float4*)(dvB + r0 + nodeLoc);
    float dn[4] = {dn4.x, dn4.y, dn4.z, dn4.w};
    #pragma unroll
    for (int nf = 0; nf < NFO; nf++) {
      int fo = wf * (F_OUT / 4) + (nf << 4) + l15;
      float bb = bias[fo];
      float v[4];
      #pragma unroll
      for (int j = 0; j < 4; j++) v[j] = fmaxf(acc2[am][nf][j] + bb, 0.f);
      if (!FINAL) {
        ushort4 p;
        p.x = (unsigned short)f2bf(v[0] * dn[0]);
        p.y = (unsigned short)f2bf(v[1] * dn[1]);
        p.z = (unsigned short)f2bf(v[2] * dn[2]);
        p.w = (unsigned short)f2bf(v[3] * dn[3]);
        size_t e = (size_t)bw * (F_OUT * 1024) + ((size_t)(fo >> 4) << 14)
                 + ((size_t)((rb << 2) + (wr << 1) + (am >> 1)) << 9)
                 + ((size_t)(((am & 1) << 1) + (l4 >> 1)) << 7)
                 + ((fo & 15) << 3) + ((l4 & 1) << 2);
        *(ushort4*)(Gout + e) = p;
      } else {
        float* ob = Out + ((size_t)(bw << 10) + r0 + nodeLoc) * F_OUT + fo;
        ob[0]         = v[0];
        ob[F_OUT]     = v[1];
        ob[2 * F_OUT] = v[2];
        ob[3 * F_OUT] = v[3];
      }
    }
  }
}

extern "C" void kernel_launch(void* const* d_in, const int* in_sizes, int n_in,
                              void* d_out, int out_size, void* d_ws, size_t ws_size,
                              hipStream_t stream) {
  const float* X   = (const float*)d_in[0];
  const float* adj = (const float*)d_in[1];
  const float* W1  = (const float*)d_in[2];
  const float* b1  = (const float*)d_in[3];
  const float* W2  = (const float*)d_in[4];
  const float* b2  = (const float*)d_in[5];
  const float* W3  = (const float*)d_in[6];
  const float* b3  = (const float*)d_in[7];
  float* out = (float*)d_out;

  char* ws = (char*)d_ws;
  float* dinv = (float*)ws;                              // 128 KB
  short* WT1  = (short*)(ws + 131072);                   // 128 KB
  short* WT2  = (short*)(ws + 262144);                   // 128 KB
  short* WT3  = (short*)(ws + 393216);                   //  64 KB
  short* bufA = (short*)(ws + 458752);                   //  16 MB
  short* bufB = (short*)(ws + 458752 + 16777216);        //  16 MB
  short* Ahat = (short*)(ws + 458752 + 2 * 16777216);    //  64 MB

  dinv_cast<<<2048, 256, 0, stream>>>(adj, dinv, Ahat);
  preproc_xw<<<2688, 256, 0, stream>>>(X, dinv, bufA, W1, W2, W3, WT1, WT2, WT3);

  gcn_layer<256, false><<<256, 512, 0, stream>>>(Ahat, dinv, bufA, WT1, b1, bufB, nullptr);
  gcn_layer<256, false><<<256, 512, 0, stream>>>(Ahat, dinv, bufB, WT2, b2, bufA, nullptr);
  gcn_layer<128, true ><<<256, 512, 0, stream>>>(Ahat, dinv, bufA, WT3, b3, nullptr, out);
}